// Round 1
// baseline (419.732 us; speedup 1.0000x reference)
//
#include <hip/hip_runtime.h>

// KbInterpForw: table-based KB NUFFT interpolation, forward.
// x: (2,16,2,512,512) f32, om: (2,2,262144) f32, tables: (2,6145) f32 each.
// out: (2,16,2,262144) f32.

#define KLEN      262144      // 2^18
#define GX        512
#define GY        512
#define NCOILS    16
#define NBATCH    2
#define TBL_LEN   6145        // 6*1024+1
#define TBL_CTR   3072
#define PLANE     (GX*GY)     // 262144 floats per (c,ri) plane

// ---------------------------------------------------------------------------
// Transpose x[b][c][ri][kx][ky] -> xt[b][kx][ky][q] as float4 (q picks coils
// 2q,2q+1: {re0,im0,re1,im1}). One float4 output per thread; writes perfectly
// coalesced, reads 32B-segmented (L1 absorbs the other half-line).
// ---------------------------------------------------------------------------
__global__ __launch_bounds__(256) void transpose_kernel(
    const float* __restrict__ x, float4* __restrict__ xt)
{
    int i  = blockIdx.x * blockDim.x + threadIdx.x;   // [0, 2*512*512*8)
    int q  = i & 7;
    int ky = (i >> 3) & 511;
    int kx = (i >> 12) & 511;
    int b  = i >> 21;
    size_t base = (size_t)(b * NCOILS + 2 * q) * (2 * PLANE) + (size_t)kx * GY + ky;
    float4 v;
    v.x = x[base];                 // coil 2q   re
    v.y = x[base + PLANE];         // coil 2q   im
    v.z = x[base + 2 * PLANE];     // coil 2q+1 re
    v.w = x[base + 3 * PLANE];     // coil 2q+1 im
    xt[i] = v;
}

// ---------------------------------------------------------------------------
// Main interp: 8 lanes per k-point; lane handles coils 2*lane, 2*lane+1.
// ---------------------------------------------------------------------------
__global__ __launch_bounds__(256) void interp_kernel(
    const float*  __restrict__ om,
    const float*  __restrict__ t0,
    const float*  __restrict__ t1,
    const float4* __restrict__ xt,
    float*        __restrict__ out)
{
    const int tid  = blockIdx.x * blockDim.x + threadIdx.x;
    const int lane = tid & 7;
    const int p    = tid >> 3;            // point index in [0, NBATCH*KLEN)
    const int b    = p >> 18;             // KLEN = 2^18
    const int m    = p & (KLEN - 1);

    const float om0 = om[(size_t)(b * 2 + 0) * KLEN + m];
    const float om1 = om[(size_t)(b * 2 + 1) * KLEN + m];

    const float TWO_PI = 6.2831853071795864769f;      // rounds to 0x40C90FDB
    const float tm0 = (om0 * 512.0f) / TWO_PI;
    const float tm1 = (om1 * 512.0f) / TWO_PI;

    const float koff0 = 1.0f + floorf(tm0 - 3.0f);
    const float koff1 = 1.0f + floorf(tm1 - 3.0f);
    const int   k0    = (int)koff0;
    const int   k1    = (int)koff1;

    float c0r[6], c0i[6], c1r[6], c1i[6];
    int   roff[6], coff[6];
#pragma unroll
    for (int j = 0; j < 6; ++j) {
        const float g0 = koff0 + (float)j;
        const int   d0 = (int)rintf((tm0 - g0) * 1024.0f) + TBL_CTR;
        c0r[j] = t0[d0];
        c0i[j] = t0[TBL_LEN + d0];
        const float g1 = koff1 + (float)j;
        const int   d1 = (int)rintf((tm1 - g1) * 1024.0f) + TBL_CTR;
        c1r[j] = t1[d1];
        c1i[j] = t1[TBL_LEN + d1];
        roff[j] = (k0 + j) & 511;          // == mod for pow2, incl. negatives
        coff[j] = (k1 + j) & 511;
    }

    const float4* rec = xt + ((size_t)b << 21);   // b*512*512*8
    float a0r = 0.f, a0i = 0.f, a1r = 0.f, a1i = 0.f;
#pragma unroll
    for (int j0 = 0; j0 < 6; ++j0) {
        const float4* rowp = rec + ((size_t)roff[j0] << 12) + lane;  // *512*8
        const float ar = c0r[j0], ai = c0i[j0];
#pragma unroll
        for (int j1 = 0; j1 < 6; ++j1) {
            const float br = c1r[j1], bi = c1i[j1];
            const float cr = ar * br - ai * bi;
            const float ci = ar * bi + ai * br;
            const float4 v = rowp[coff[j1] << 3];
            a0r += cr * v.x - ci * v.y;
            a0i += cr * v.y + ci * v.x;
            a1r += cr * v.z - ci * v.w;
            a1i += cr * v.w + ci * v.z;
        }
    }

    // phase twist: exp(i * (om0+om1)*128)
    const float ph = om0 * 128.0f + om1 * 128.0f;
    const float s = sinf(ph), c = cosf(ph);
    const float y0r = a0r * c - a0i * s;
    const float y0i = a0r * s + a0i * c;
    const float y1r = a1r * c - a1i * s;
    const float y1i = a1r * s + a1i * c;

    const int cA = 2 * lane;
    size_t ob = ((size_t)(b * NCOILS + cA) * 2) * KLEN + m;
    out[ob]             = y0r;
    out[ob + KLEN]      = y0i;
    out[ob + 2 * KLEN]  = y1r;   // coil 2*lane+1 real
    out[ob + 3 * KLEN]  = y1i;   // coil 2*lane+1 imag
}

// ---------------------------------------------------------------------------
// Fallback (no workspace): one thread per point, scalar gathers from original
// layout. Correct but slow; only used if ws_size is too small.
// ---------------------------------------------------------------------------
__global__ __launch_bounds__(256) void interp_fallback(
    const float* __restrict__ om,
    const float* __restrict__ t0,
    const float* __restrict__ t1,
    const float* __restrict__ x,
    float*       __restrict__ out)
{
    const int p = blockIdx.x * blockDim.x + threadIdx.x;
    const int b = p >> 18;
    const int m = p & (KLEN - 1);

    const float om0 = om[(size_t)(b * 2 + 0) * KLEN + m];
    const float om1 = om[(size_t)(b * 2 + 1) * KLEN + m];
    const float TWO_PI = 6.2831853071795864769f;
    const float tm0 = (om0 * 512.0f) / TWO_PI;
    const float tm1 = (om1 * 512.0f) / TWO_PI;
    const float koff0 = 1.0f + floorf(tm0 - 3.0f);
    const float koff1 = 1.0f + floorf(tm1 - 3.0f);
    const int k0 = (int)koff0, k1 = (int)koff1;

    float c0r[6], c0i[6], c1r[6], c1i[6];
    int roff[6], coff[6];
#pragma unroll
    for (int j = 0; j < 6; ++j) {
        const float g0 = koff0 + (float)j;
        const int d0 = (int)rintf((tm0 - g0) * 1024.0f) + TBL_CTR;
        c0r[j] = t0[d0];
        c0i[j] = t0[TBL_LEN + d0];
        const float g1 = koff1 + (float)j;
        const int d1 = (int)rintf((tm1 - g1) * 1024.0f) + TBL_CTR;
        c1r[j] = t1[d1];
        c1i[j] = t1[TBL_LEN + d1];
        roff[j] = (k0 + j) & 511;
        coff[j] = (k1 + j) & 511;
    }

    float accr[NCOILS], acci[NCOILS];
#pragma unroll
    for (int c = 0; c < NCOILS; ++c) { accr[c] = 0.f; acci[c] = 0.f; }

    const float* xb = x + (size_t)b * NCOILS * 2 * PLANE;
#pragma unroll
    for (int j0 = 0; j0 < 6; ++j0) {
        const float ar = c0r[j0], ai = c0i[j0];
        const int rb = roff[j0] * GY;
#pragma unroll
        for (int j1 = 0; j1 < 6; ++j1) {
            const float br = c1r[j1], bi = c1i[j1];
            const float cr = ar * br - ai * bi;
            const float ci = ar * bi + ai * br;
            const int ai_idx = rb + coff[j1];
#pragma unroll
            for (int c = 0; c < NCOILS; ++c) {
                const float dr = xb[(size_t)c * (2 * PLANE) + ai_idx];
                const float di = xb[(size_t)c * (2 * PLANE) + PLANE + ai_idx];
                accr[c] += cr * dr - ci * di;
                acci[c] += cr * di + ci * dr;
            }
        }
    }

    const float ph = om0 * 128.0f + om1 * 128.0f;
    const float s = sinf(ph), c = cosf(ph);
#pragma unroll
    for (int cc = 0; cc < NCOILS; ++cc) {
        const float yr = accr[cc] * c - acci[cc] * s;
        const float yi = accr[cc] * s + acci[cc] * c;
        size_t ob = ((size_t)(b * NCOILS + cc) * 2) * KLEN + m;
        out[ob]        = yr;
        out[ob + KLEN] = yi;
    }
}

extern "C" void kernel_launch(void* const* d_in, const int* in_sizes, int n_in,
                              void* d_out, int out_size, void* d_ws, size_t ws_size,
                              hipStream_t stream)
{
    const float* x  = (const float*)d_in[0];
    const float* om = (const float*)d_in[1];
    const float* t0 = (const float*)d_in[2];
    const float* t1 = (const float*)d_in[3];
    float* out = (float*)d_out;

    const size_t xt_bytes = (size_t)NBATCH * GX * GY * NCOILS * 2 * sizeof(float); // 67 MB

    if (ws_size >= xt_bytes) {
        float4* xt = (float4*)d_ws;
        {
            const int total = NBATCH * GX * GY * 8;  // one float4 per thread
            transpose_kernel<<<total / 256, 256, 0, stream>>>(x, xt);
        }
        {
            const int total = NBATCH * KLEN * 8;     // 8 lanes per point
            interp_kernel<<<total / 256, 256, 0, stream>>>(om, t0, t1, xt, out);
        }
    } else {
        const int total = NBATCH * KLEN;
        interp_fallback<<<total / 256, 256, 0, stream>>>(om, t0, t1, x, out);
    }
}

// Round 2
// 349.697 us; speedup vs baseline: 1.2003x; 1.2003x over previous
//
#include <hip/hip_runtime.h>
#include <hip/hip_fp16.h>

// KbInterpForw: table-based KB NUFFT interpolation, forward.
// x: (2,16,2,512,512) f32, om: (2,2,262144) f32, tables: (2,6145) f32 each.
// out: (2,16,2,262144) f32.
//
// Strategy (R2): grid transposed to per-cell records of 16 coils x complex in
// FP16 (64 B/record, one cache line). 4 lanes per k-point, each lane owns 4
// coils and loads one 16 B chunk of the record per tap.

#define KLEN      262144      // 2^18
#define GX        512
#define GY        512
#define NCOILS    16
#define NBATCH    2
#define TBL_LEN   6145        // 6*1024+1
#define TBL_CTR   3072
#define PLANE     (GX*GY)

struct alignas(16) H8 { __half2 h[4]; };   // 4 coils' (re,im) in fp16 = 16 B

// ---------------------------------------------------------------------------
// Transpose+downconvert: x[b][c][ri][kx][ky] (f32 planes) ->
// xt records: xt[b][kx][ky] = 16 x half2(re,im), 64 B each.
// Thread = one 16 B chunk (4 coils) of one record. Store: consecutive lanes
// write consecutive 16 B -> perfectly coalesced dwordx4.
// ---------------------------------------------------------------------------
__global__ __launch_bounds__(256) void transpose_fp16(
    const float* __restrict__ x, float4* __restrict__ xt)
{
    const int tid  = blockIdx.x * blockDim.x + threadIdx.x;  // [0, 2*262144*4)
    const int q    = tid & 3;          // which 4-coil chunk
    const int r    = tid >> 2;         // record = b*PLANE + cell
    const int b    = r >> 18;
    const int cell = r & (PLANE - 1);

    const float* xb = x + (size_t)b * NCOILS * 2 * PLANE + cell;
    H8 v;
#pragma unroll
    for (int cc = 0; cc < 4; ++cc) {
        const int c = q * 4 + cc;
        const float re = xb[(size_t)(2 * c)     * PLANE];
        const float im = xb[(size_t)(2 * c + 1) * PLANE];
        v.h[cc] = __floats2half2_rn(re, im);
    }
    xt[tid] = *(const float4*)&v;
}

// ---------------------------------------------------------------------------
// Main interp: 4 lanes per k-point; lane owns coils 4*lane .. 4*lane+3.
// Per tap: one dwordx4 (16 B of the 64 B record), 8 f16->f32 cvt, 16 FMA.
// ---------------------------------------------------------------------------
__global__ __launch_bounds__(256) void interp_fp16(
    const float*  __restrict__ om,
    const float*  __restrict__ t0,
    const float*  __restrict__ t1,
    const float4* __restrict__ xt,
    float*        __restrict__ out)
{
    const int tid  = blockIdx.x * blockDim.x + threadIdx.x;
    const int lane = tid & 3;
    const int p    = tid >> 2;            // point index in [0, NBATCH*KLEN)
    const int b    = p >> 18;             // KLEN = 2^18
    const int m    = p & (KLEN - 1);

    const float om0 = om[(size_t)(b * 2 + 0) * KLEN + m];
    const float om1 = om[(size_t)(b * 2 + 1) * KLEN + m];

    const float TWO_PI = 6.2831853071795864769f;
    const float tm0 = (om0 * 512.0f) / TWO_PI;
    const float tm1 = (om1 * 512.0f) / TWO_PI;

    const float koff0 = 1.0f + floorf(tm0 - 3.0f);
    const float koff1 = 1.0f + floorf(tm1 - 3.0f);
    const int   k0    = (int)koff0;
    const int   k1    = (int)koff1;

    float c0r[6], c0i[6], c1r[6], c1i[6];
    int   roff[6], coff[6];
#pragma unroll
    for (int j = 0; j < 6; ++j) {
        const float g0 = koff0 + (float)j;
        const int   d0 = (int)rintf((tm0 - g0) * 1024.0f) + TBL_CTR;
        c0r[j] = t0[d0];
        c0i[j] = t0[TBL_LEN + d0];
        const float g1 = koff1 + (float)j;
        const int   d1 = (int)rintf((tm1 - g1) * 1024.0f) + TBL_CTR;
        c1r[j] = t1[d1];
        c1i[j] = t1[TBL_LEN + d1];
        roff[j] = (k0 + j) & 511;          // pow2 mod, handles negatives
        coff[j] = (k1 + j) & 511;
    }

    const float4* rec = xt + ((size_t)b << 20);   // b * PLANE * 4 chunks
    float acr[4] = {0.f, 0.f, 0.f, 0.f};
    float aci[4] = {0.f, 0.f, 0.f, 0.f};
#pragma unroll
    for (int j0 = 0; j0 < 6; ++j0) {
        const float4* rowp = rec + ((size_t)roff[j0] << 11) + lane;  // *512*4
        const float ar = c0r[j0], ai = c0i[j0];
#pragma unroll
        for (int j1 = 0; j1 < 6; ++j1) {
            const float br = c1r[j1], bi = c1i[j1];
            const float cr = ar * br - ai * bi;
            const float ci = ar * bi + ai * br;
            const float4 raw = rowp[coff[j1] << 2];
            const H8 v = *(const H8*)&raw;
#pragma unroll
            for (int cc = 0; cc < 4; ++cc) {
                const float2 d = __half22float2(v.h[cc]);
                acr[cc] += cr * d.x - ci * d.y;
                aci[cc] += cr * d.y + ci * d.x;
            }
        }
    }

    // phase twist: exp(i * (om0+om1)*128)
    const float ph = om0 * 128.0f + om1 * 128.0f;
    const float s = sinf(ph), c = cosf(ph);

#pragma unroll
    for (int cc = 0; cc < 4; ++cc) {
        const float yr = acr[cc] * c - aci[cc] * s;
        const float yi = acr[cc] * s + aci[cc] * c;
        const int coil = lane * 4 + cc;
        const size_t ob = ((size_t)(b * NCOILS + coil) * 2) * KLEN + m;
        out[ob]        = yr;
        out[ob + KLEN] = yi;
    }
}

// ---------------------------------------------------------------------------
// Fallback (no workspace): one thread per point, scalar gathers from original
// layout. Correct but slow; only used if ws_size is too small.
// ---------------------------------------------------------------------------
__global__ __launch_bounds__(256) void interp_fallback(
    const float* __restrict__ om,
    const float* __restrict__ t0,
    const float* __restrict__ t1,
    const float* __restrict__ x,
    float*       __restrict__ out)
{
    const int p = blockIdx.x * blockDim.x + threadIdx.x;
    const int b = p >> 18;
    const int m = p & (KLEN - 1);

    const float om0 = om[(size_t)(b * 2 + 0) * KLEN + m];
    const float om1 = om[(size_t)(b * 2 + 1) * KLEN + m];
    const float TWO_PI = 6.2831853071795864769f;
    const float tm0 = (om0 * 512.0f) / TWO_PI;
    const float tm1 = (om1 * 512.0f) / TWO_PI;
    const float koff0 = 1.0f + floorf(tm0 - 3.0f);
    const float koff1 = 1.0f + floorf(tm1 - 3.0f);
    const int k0 = (int)koff0, k1 = (int)koff1;

    float c0r[6], c0i[6], c1r[6], c1i[6];
    int roff[6], coff[6];
#pragma unroll
    for (int j = 0; j < 6; ++j) {
        const float g0 = koff0 + (float)j;
        const int d0 = (int)rintf((tm0 - g0) * 1024.0f) + TBL_CTR;
        c0r[j] = t0[d0];
        c0i[j] = t0[TBL_LEN + d0];
        const float g1 = koff1 + (float)j;
        const int d1 = (int)rintf((tm1 - g1) * 1024.0f) + TBL_CTR;
        c1r[j] = t1[d1];
        c1i[j] = t1[TBL_LEN + d1];
        roff[j] = (k0 + j) & 511;
        coff[j] = (k1 + j) & 511;
    }

    float accr[NCOILS], acci[NCOILS];
#pragma unroll
    for (int c = 0; c < NCOILS; ++c) { accr[c] = 0.f; acci[c] = 0.f; }

    const float* xb = x + (size_t)b * NCOILS * 2 * PLANE;
#pragma unroll
    for (int j0 = 0; j0 < 6; ++j0) {
        const float ar = c0r[j0], ai = c0i[j0];
        const int rb = roff[j0] * GY;
#pragma unroll
        for (int j1 = 0; j1 < 6; ++j1) {
            const float br = c1r[j1], bi = c1i[j1];
            const float cr = ar * br - ai * bi;
            const float ci = ar * bi + ai * br;
            const int ai_idx = rb + coff[j1];
#pragma unroll
            for (int c = 0; c < NCOILS; ++c) {
                const float dr = xb[(size_t)c * (2 * PLANE) + ai_idx];
                const float di = xb[(size_t)c * (2 * PLANE) + PLANE + ai_idx];
                accr[c] += cr * dr - ci * di;
                acci[c] += cr * di + ci * dr;
            }
        }
    }

    const float ph = om0 * 128.0f + om1 * 128.0f;
    const float s = sinf(ph), c = cosf(ph);
#pragma unroll
    for (int cc = 0; cc < NCOILS; ++cc) {
        const float yr = accr[cc] * c - acci[cc] * s;
        const float yi = accr[cc] * s + acci[cc] * c;
        size_t ob = ((size_t)(b * NCOILS + cc) * 2) * KLEN + m;
        out[ob]        = yr;
        out[ob + KLEN] = yi;
    }
}

extern "C" void kernel_launch(void* const* d_in, const int* in_sizes, int n_in,
                              void* d_out, int out_size, void* d_ws, size_t ws_size,
                              hipStream_t stream)
{
    const float* x  = (const float*)d_in[0];
    const float* om = (const float*)d_in[1];
    const float* t0 = (const float*)d_in[2];
    const float* t1 = (const float*)d_in[3];
    float* out = (float*)d_out;

    // fp16 records: 2 batches * 512*512 cells * 64 B = 33.5 MB
    const size_t xt_bytes = (size_t)NBATCH * PLANE * NCOILS * 2 * sizeof(__half);

    if (ws_size >= xt_bytes) {
        float4* xt = (float4*)d_ws;
        {
            const int total = NBATCH * PLANE * 4;   // one 16 B chunk per thread
            transpose_fp16<<<total / 256, 256, 0, stream>>>(x, xt);
        }
        {
            const int total = NBATCH * KLEN * 4;    // 4 lanes per point
            interp_fp16<<<total / 256, 256, 0, stream>>>(om, t0, t1, xt, out);
        }
    } else {
        const int total = NBATCH * KLEN;
        interp_fallback<<<total / 256, 256, 0, stream>>>(om, t0, t1, x, out);
    }
}